// Round 9
// baseline (292.805 us; speedup 1.0000x reference)
//
#include <hip/hip_runtime.h>
#include <hip/hip_bf16.h>

// B=2, T=2048, D=1024, H=16, Hd=64. Inputs/outputs f32; compute bf16 MFMA.

typedef __bf16 bf16;
typedef bf16 bf16x8 __attribute__((ext_vector_type(8)));
typedef bf16 bf16x4 __attribute__((ext_vector_type(4)));
typedef float f32x4 __attribute__((ext_vector_type(4)));

#define MFMA16(a, b, c) __builtin_amdgcn_mfma_f32_16x16x32_bf16((a), (b), (c), 0, 0, 0)

static constexpr int D_MODEL = 1024;
static constexpr int NH = 16;
static constexpr int HD = 64;
static constexpr int SEQ = 2048;
static constexpr int NB = 2;
static constexpr float QSCALE = 0.125f * 1.44269504088896340736f; // 1/sqrt(64)*log2(e)

__device__ __forceinline__ bf16x8 cvt8(const float* p) {
    float4 u0 = *(const float4*)p;
    float4 u1 = *(const float4*)(p + 4);
    bf16x8 v = { (bf16)u0.x, (bf16)u0.y, (bf16)u0.z, (bf16)u0.w,
                 (bf16)u1.x, (bf16)u1.y, (bf16)u1.z, (bf16)u1.w };
    return v;
}

// async global->LDS, 16 B per lane (LDS dest = wave-uniform base + lane*16).
__device__ __forceinline__ void async16(const bf16* g, bf16* l) {
    __builtin_amdgcn_global_load_lds(
        (const __attribute__((address_space(1))) void*)g,
        (__attribute__((address_space(3))) void*)l, 16, 0, 0);
}

// ---------------------------------------------------------------------------
// Kernel 0: f32 -> bf16 cast (vector x8).
// ---------------------------------------------------------------------------
__global__ __launch_bounds__(256)
void k_cast(const float* __restrict__ in, bf16* __restrict__ out, int n8)
{
    int i = blockIdx.x * 256 + threadIdx.x;
    if (i < n8) *(bf16x8*)&out[(size_t)i * 8] = cvt8(&in[(size_t)i * 8]);
}

// ---------------------------------------------------------------------------
// Kernel 1: QKV projection, 128x128 tile, BK=64 (16 K-iters, half the
// barriers of BK=32), global_load_lds staging into flat unpadded LDS.
// Q -> [B,H,T,64] (pre-scaled), K -> [B,H,T,64], V -> transposed [B,H,64,T].
// ---------------------------------------------------------------------------
__global__ __launch_bounds__(256)
void k_qkv(const bf16* __restrict__ x, const bf16* __restrict__ w,
           const float* __restrict__ bias,
           bf16* __restrict__ Qb, bf16* __restrict__ Kb, bf16* __restrict__ VbT)
{
    __shared__ bf16 As[128 * 64];   // 16 KB, flat
    __shared__ bf16 Ws[128 * 64];   // 16 KB

    const int tid  = threadIdx.x;
    const int wv   = tid >> 6;
    const int lane = tid & 63;
    const int lr   = lane & 15;
    const int lk   = lane >> 4;
    const int wm   = wv >> 1, wn = wv & 1;
    const int m0   = blockIdx.x * 128;
    const int n0   = blockIdx.y * 128;

    const int sRow = tid >> 3;           // 0..31
    const int sCol = (tid & 7) * 8;      // 0..56
    const int sOff = sRow * 64 + sCol;   // = 16*tid bytes

    f32x4 acc[4][4] = {};

    for (int kt = 0; kt < 1024; kt += 64) {
        __syncthreads();
        #pragma unroll
        for (int rr = 0; rr < 4; rr++) {
            async16(&x[(size_t)(m0 + rr * 32 + sRow) * 1024 + kt + sCol], &As[rr * 32 * 64 + sOff]);
            async16(&w[(size_t)(n0 + rr * 32 + sRow) * 1024 + kt + sCol], &Ws[rr * 32 * 64 + sOff]);
        }
        __syncthreads();

        #pragma unroll
        for (int kc = 0; kc < 2; kc++) {
            bf16x8 a[4], b[4];
            #pragma unroll
            for (int i = 0; i < 4; i++) {
                a[i] = *(const bf16x8*)&As[(wm * 64 + i * 16 + lr) * 64 + kc * 32 + lk * 8];
                b[i] = *(const bf16x8*)&Ws[(wn * 64 + i * 16 + lr) * 64 + kc * 32 + lk * 8];
            }
            #pragma unroll
            for (int i = 0; i < 4; i++)
                #pragma unroll
                for (int j = 0; j < 4; j++)
                    acc[i][j] = MFMA16(a[i], b[j], acc[i][j]);
        }
    }

    // C/D layout: col = lane&15, row = (lane>>4)*4 + reg
    #pragma unroll
    for (int i = 0; i < 4; i++) {
        #pragma unroll
        for (int j = 0; j < 4; j++) {
            const int gm0 = m0 + wm * 64 + i * 16 + lk * 4;
            const int gn  = n0 + wn * 64 + j * 16 + lr;
            const int sel = gn >> 10;
            const int rem = gn & 1023;
            const int h   = rem >> 6;
            const int hd  = rem & 63;
            const int bb  = gm0 >> 11;
            const int t0  = gm0 & 2047;
            if (sel == 2) {
                bf16x4 p;
                #pragma unroll
                for (int r = 0; r < 4; r++) p[r] = (bf16)(acc[i][j][r] + bias[gn]);
                *(bf16x4*)&VbT[((size_t)(bb * NH + h) * HD + hd) * SEQ + t0] = p;
            } else {
                #pragma unroll
                for (int r = 0; r < 4; r++) {
                    float v = acc[i][j][r] + bias[gn];
                    size_t idx = ((size_t)(bb * NH + h) * SEQ + t0 + r) * HD + hd;
                    if (sel == 0) Qb[idx] = (bf16)(v * QSCALE);
                    else          Kb[idx] = (bf16)v;
                }
            }
        }
    }
}

// ---------------------------------------------------------------------------
// Kernel 2: causal flash attention — split-K across waves.
// Block = 256 thr = 4 waves covering the same 32 queries; wave w does k-tiles
// kt = w, w+4, ... (serial chain <= 8 tiles). No-max softmax (associative) ->
// per-wave partial (O^T, l), combined once via LDS f32 atomicAdd. No barriers
// in the k-loop. launch_bounds(256,2): VGPR cap 256 — R8's (256,3) forced 64
// VGPRs and spilled every fragment (143 us); never cap below fragment demand.
// ---------------------------------------------------------------------------
__global__ __launch_bounds__(256, 2)
void k_attn(const bf16* __restrict__ Qb, const bf16* __restrict__ Kb,
            const bf16* __restrict__ VbT, bf16* __restrict__ AO)
{
    __shared__ bf16  Ps[128][72];   // wave w owns rows [w*32, w*32+32)
    __shared__ float cb[64][33];    // combine: [hd][q-local], padded
    __shared__ float lsb[32];       // per-q l sum

    const int tid  = threadIdx.x;
    const int wv   = tid >> 6;
    const int lane = tid & 63;
    const int lr   = lane & 15;
    const int lk   = lane >> 4;

    const int id  = blockIdx.x;
    const int bh  = id & 31;
    const int qq  = 63 - (id >> 5);       // longest blocks first
    const int nkt = (qq >> 1) + 1;        // causal 64-key tiles for this 32-q block

    for (int i = tid; i < 64 * 33; i += 256) (&cb[0][0])[i] = 0.f;
    if (tid < 32) lsb[tid] = 0.f;
    __syncthreads();

    const bf16* Qp  = Qb  + (size_t)bh * SEQ * HD;
    const bf16* Kp  = Kb  + (size_t)bh * SEQ * HD;
    const bf16* Vtp = VbT + (size_t)bh * HD * SEQ;

    const int qbase = qq * 32;
    const int qg[2] = { qbase + lr, qbase + 16 + lr };

    bf16x8 qf[2][2];
    #pragma unroll
    for (int h = 0; h < 2; h++)
        #pragma unroll
        for (int c = 0; c < 2; c++)
            qf[h][c] = *(const bf16x8*)&Qp[(size_t)(qbase + h * 16 + lr) * HD + c * 32 + lk * 8];

    f32x4 ot[2][4] = {};       // partial O^T: col=q(lr), row=hd=jh*16+lk*4+r
    float lsum[2] = { 0.f, 0.f };

    for (int kt = wv; kt < nkt; kt += 4) {
        const int k0 = kt * 64;

        // K fragments first; S depends only on these
        bf16x8 ka[4][2];
        #pragma unroll
        for (int j = 0; j < 4; j++)
            #pragma unroll
            for (int c = 0; c < 2; c++)
                ka[j][c] = *(const bf16x8*)&Kp[(size_t)(k0 + j * 16 + lr) * HD + c * 32 + lk * 8];

        // S^T[key][q] per strip: row=key=j*16+lk*4+r, col=q=lr
        f32x4 s[2][4] = {};
        #pragma unroll
        for (int j = 0; j < 4; j++) {
            #pragma unroll
            for (int c = 0; c < 2; c++) {
                s[0][j] = MFMA16(ka[j][c], qf[0][c], s[0][j]);
                s[1][j] = MFMA16(ka[j][c], qf[1][c], s[1][j]);
            }
        }

        // V fragments: issued before the exp block (VALU hides the latency)
        bf16x8 va[4][2];
        #pragma unroll
        for (int j = 0; j < 4; j++)
            #pragma unroll
            for (int c = 0; c < 2; c++)
                va[j][c] = *(const bf16x8*)&Vtp[(size_t)(j * 16 + lr) * SEQ + k0 + c * 32 + lk * 8];

        const bool diag = (kt == nkt - 1);

        // no-max softmax, HW exp (scores pre-scaled to log2 domain)
        #pragma unroll
        for (int h = 0; h < 2; h++) {
            float rs[4];
            #pragma unroll
            for (int j = 0; j < 4; j++) {
                const int keyb = k0 + j * 16 + lk * 4;
                f32x4 p;
                #pragma unroll
                for (int r = 0; r < 4; r++) {
                    float e = __builtin_amdgcn_exp2f(s[h][j][r]);
                    if (diag) e = (keyb + r > qg[h]) ? 0.f : e;
                    p[r] = e;
                }
                s[h][j] = p;
                rs[j] = (p[0] + p[1]) + (p[2] + p[3]);
            }
            lsum[h] += (rs[0] + rs[1]) + (rs[2] + rs[3]);
        }

        // P -> LDS [q][key], packed b64 (wave-local rows; no barrier)
        #pragma unroll
        for (int h = 0; h < 2; h++)
            #pragma unroll
            for (int j = 0; j < 4; j++) {
                bf16x4 p4 = { (bf16)s[h][j][0], (bf16)s[h][j][1],
                              (bf16)s[h][j][2], (bf16)s[h][j][3] };
                *(bf16x4*)&Ps[wv * 32 + h * 16 + lr][j * 16 + lk * 4] = p4;
            }

        // O^T += Vt · P^T
        #pragma unroll
        for (int c = 0; c < 2; c++) {
            bf16x8 pb0 = *(const bf16x8*)&Ps[wv * 32      + lr][c * 32 + lk * 8];
            bf16x8 pb1 = *(const bf16x8*)&Ps[wv * 32 + 16 + lr][c * 32 + lk * 8];
            #pragma unroll
            for (int jh = 0; jh < 4; jh++) {
                ot[0][jh] = MFMA16(va[jh][c], pb0, ot[0][jh]);
                ot[1][jh] = MFMA16(va[jh][c], pb1, ot[1][jh]);
            }
        }
    }

    // fold this wave's partials into the block accumulators
    #pragma unroll
    for (int h = 0; h < 2; h++) {
        lsum[h] += __shfl_xor(lsum[h], 16);
        lsum[h] += __shfl_xor(lsum[h], 32);
        if (lk == 0) atomicAdd(&lsb[h * 16 + lr], lsum[h]);
        #pragma unroll
        for (int jh = 0; jh < 4; jh++)
            #pragma unroll
            for (int r = 0; r < 4; r++)
                atomicAdd(&cb[jh * 16 + lk * 4 + r][h * 16 + lr], ot[h][jh][r]);
    }
    __syncthreads();

    // epilogue: thread t -> q = t>>3, hd chunk = (t&7)*8; b128 store
    {
        const int b_ = bh >> 4, h_ = bh & 15;
        const int ql = tid >> 3;
        const int hc = (tid & 7) * 8;
        const float inv = 1.0f / lsb[ql];
        bf16x8 o8;
        #pragma unroll
        for (int e = 0; e < 8; e++) o8[e] = (bf16)(cb[hc + e][ql] * inv);
        const size_t base = ((size_t)(b_ * SEQ + qbase + ql)) * D_MODEL + h_ * HD + hc;
        *(bf16x8*)&AO[base] = o8;
    }
}

// ---------------------------------------------------------------------------
// Kernel 3: output projection, 128x64 tile, BK=64, global_load_lds staging.
// ---------------------------------------------------------------------------
__global__ __launch_bounds__(256)
void k_oproj(const bf16* __restrict__ a_, const bf16* __restrict__ w,
             const float* __restrict__ bias, float* __restrict__ out)
{
    __shared__ bf16 As[128 * 64];   // 16 KB
    __shared__ bf16 Ws[64 * 64];    // 8 KB

    const int tid  = threadIdx.x;
    const int wv   = tid >> 6;
    const int lane = tid & 63;
    const int lr   = lane & 15;
    const int lk   = lane >> 4;
    const int wm   = wv >> 1, wn = wv & 1;
    const int m0   = blockIdx.x * 128;
    const int n0   = blockIdx.y * 64;

    const int sRow = tid >> 3;
    const int sCol = (tid & 7) * 8;
    const int sOff = sRow * 64 + sCol;   // = 16*tid bytes

    f32x4 acc[4][2] = {};

    for (int kt = 0; kt < 1024; kt += 64) {
        __syncthreads();
        #pragma unroll
        for (int rr = 0; rr < 4; rr++)
            async16(&a_[(size_t)(m0 + rr * 32 + sRow) * 1024 + kt + sCol], &As[rr * 32 * 64 + sOff]);
        #pragma unroll
        for (int rr = 0; rr < 2; rr++)
            async16(&w[(size_t)(n0 + rr * 32 + sRow) * 1024 + kt + sCol], &Ws[rr * 32 * 64 + sOff]);
        __syncthreads();

        #pragma unroll
        for (int kc = 0; kc < 2; kc++) {
            bf16x8 a[4], b[2];
            #pragma unroll
            for (int i = 0; i < 4; i++)
                a[i] = *(const bf16x8*)&As[(wm * 64 + i * 16 + lr) * 64 + kc * 32 + lk * 8];
            #pragma unroll
            for (int j = 0; j < 2; j++)
                b[j] = *(const bf16x8*)&Ws[(wn * 32 + j * 16 + lr) * 64 + kc * 32 + lk * 8];
            #pragma unroll
            for (int i = 0; i < 4; i++)
                #pragma unroll
                for (int j = 0; j < 2; j++)
                    acc[i][j] = MFMA16(a[i], b[j], acc[i][j]);
        }
    }

    #pragma unroll
    for (int i = 0; i < 4; i++) {
        #pragma unroll
        for (int j = 0; j < 2; j++) {
            #pragma unroll
            for (int r = 0; r < 4; r++) {
                int gm = m0 + wm * 64 + i * 16 + lk * 4 + r;
                int gn = n0 + wn * 32 + j * 16 + lr;
                out[(size_t)gm * 1024 + gn] = acc[i][j][r] + bias[gn];
            }
        }
    }
}

// ---------------------------------------------------------------------------
extern "C" void kernel_launch(void* const* d_in, const int* in_sizes, int n_in,
                              void* d_out, int out_size, void* d_ws, size_t ws_size,
                              hipStream_t stream)
{
    const float* x     = (const float*)d_in[0];
    const float* qkv_w = (const float*)d_in[1];
    const float* qkv_b = (const float*)d_in[2];
    const float* out_w = (const float*)d_in[3];
    const float* out_b = (const float*)d_in[4];
    float* out = (float*)d_out;

    const size_t SZ = (size_t)NB * NH * SEQ * HD;      // 4,194,304
    bf16* Qb  = (bf16*)d_ws;
    bf16* Kb  = Qb + SZ;
    bf16* VbT = Kb + SZ;
    bf16* AO  = VbT + SZ;
    bf16* xb  = AO + SZ;
    bf16* wqb = xb + SZ;
    bf16* wob = wqb + (size_t)3 * D_MODEL * D_MODEL;

    hipLaunchKernelGGL(k_cast, dim3(2048), dim3(256), 0, stream, x,     xb,  524288);
    hipLaunchKernelGGL(k_cast, dim3(1536), dim3(256), 0, stream, qkv_w, wqb, 393216);
    hipLaunchKernelGGL(k_cast, dim3(512),  dim3(256), 0, stream, out_w, wob, 131072);

    hipLaunchKernelGGL(k_qkv, dim3(32, 24), dim3(256), 0, stream,
                       xb, wqb, qkv_b, Qb, Kb, VbT);
    hipLaunchKernelGGL(k_attn, dim3(2048), dim3(256), 0, stream,
                       Qb, Kb, VbT, AO);
    hipLaunchKernelGGL(k_oproj, dim3(32, 16), dim3(256), 0, stream,
                       AO, wob, out_b, out);
}

// Round 10
// 203.080 us; speedup vs baseline: 1.4418x; 1.4418x over previous
//
#include <hip/hip_runtime.h>
#include <hip/hip_bf16.h>

// B=2, T=2048, D=1024, H=16, Hd=64. Inputs/outputs f32; compute bf16 MFMA.

typedef __bf16 bf16;
typedef bf16 bf16x8 __attribute__((ext_vector_type(8)));
typedef bf16 bf16x4 __attribute__((ext_vector_type(4)));
typedef float f32x4 __attribute__((ext_vector_type(4)));

#define MFMA16(a, b, c) __builtin_amdgcn_mfma_f32_16x16x32_bf16((a), (b), (c), 0, 0, 0)

static constexpr int D_MODEL = 1024;
static constexpr int NH = 16;
static constexpr int HD = 64;
static constexpr int SEQ = 2048;
static constexpr int NB = 2;
static constexpr float QSCALE = 0.125f * 1.44269504088896340736f; // 1/sqrt(64)*log2(e)

__device__ __forceinline__ bf16x8 cvt8(const float* p) {
    float4 u0 = *(const float4*)p;
    float4 u1 = *(const float4*)(p + 4);
    bf16x8 v = { (bf16)u0.x, (bf16)u0.y, (bf16)u0.z, (bf16)u0.w,
                 (bf16)u1.x, (bf16)u1.y, (bf16)u1.z, (bf16)u1.w };
    return v;
}

// async global->LDS, 16 B per lane (LDS dest = wave-uniform base + lane*16).
__device__ __forceinline__ void async16(const bf16* g, bf16* l) {
    __builtin_amdgcn_global_load_lds(
        (const __attribute__((address_space(1))) void*)g,
        (__attribute__((address_space(3))) void*)l, 16, 0, 0);
}

// ---------------------------------------------------------------------------
// Kernel 0: f32 -> bf16 cast (vector x8).
// ---------------------------------------------------------------------------
__global__ __launch_bounds__(256)
void k_cast(const float* __restrict__ in, bf16* __restrict__ out, int n8)
{
    int i = blockIdx.x * 256 + threadIdx.x;
    if (i < n8) *(bf16x8*)&out[(size_t)i * 8] = cvt8(&in[(size_t)i * 8]);
}

// ---------------------------------------------------------------------------
// Kernel 1: QKV projection, 128x128 tile, BK=32 (BK=64 regressed: R9,
// occupancy cliff per m132), global_load_lds staging, flat unpadded LDS.
// Q -> [B,H,T,64] (pre-scaled), K -> [B,H,T,64], V -> transposed [B,H,64,T].
// ---------------------------------------------------------------------------
__global__ __launch_bounds__(256)
void k_qkv(const bf16* __restrict__ x, const bf16* __restrict__ w,
           const float* __restrict__ bias,
           bf16* __restrict__ Qb, bf16* __restrict__ Kb, bf16* __restrict__ VbT)
{
    __shared__ bf16 As[128 * 32];   // 8 KB, flat
    __shared__ bf16 Ws[128 * 32];

    const int tid  = threadIdx.x;
    const int wv   = tid >> 6;
    const int lane = tid & 63;
    const int lr   = lane & 15;
    const int lk   = lane >> 4;
    const int wm   = wv >> 1, wn = wv & 1;
    const int m0   = blockIdx.x * 128;
    const int n0   = blockIdx.y * 128;

    const int sRow = tid >> 2;           // 0..63
    const int sCol = (tid & 3) * 8;      // 0,8,16,24
    const int sOff = sRow * 32 + sCol;   // = 16*tid bytes

    f32x4 acc[4][4] = {};

    for (int kt = 0; kt < 1024; kt += 32) {
        __syncthreads();
        async16(&x[(size_t)(m0 + sRow     ) * 1024 + kt + sCol], &As[sOff]);
        async16(&x[(size_t)(m0 + 64 + sRow) * 1024 + kt + sCol], &As[64 * 32 + sOff]);
        async16(&w[(size_t)(n0 + sRow     ) * 1024 + kt + sCol], &Ws[sOff]);
        async16(&w[(size_t)(n0 + 64 + sRow) * 1024 + kt + sCol], &Ws[64 * 32 + sOff]);
        __syncthreads();

        bf16x8 a[4], b[4];
        #pragma unroll
        for (int i = 0; i < 4; i++) {
            a[i] = *(const bf16x8*)&As[(wm * 64 + i * 16 + lr) * 32 + lk * 8];
            b[i] = *(const bf16x8*)&Ws[(wn * 64 + i * 16 + lr) * 32 + lk * 8];
        }
        #pragma unroll
        for (int i = 0; i < 4; i++)
            #pragma unroll
            for (int j = 0; j < 4; j++)
                acc[i][j] = MFMA16(a[i], b[j], acc[i][j]);
    }

    // C/D layout: col = lane&15, row = (lane>>4)*4 + reg
    #pragma unroll
    for (int i = 0; i < 4; i++) {
        #pragma unroll
        for (int j = 0; j < 4; j++) {
            const int gm0 = m0 + wm * 64 + i * 16 + lk * 4;
            const int gn  = n0 + wn * 64 + j * 16 + lr;
            const int sel = gn >> 10;
            const int rem = gn & 1023;
            const int h   = rem >> 6;
            const int hd  = rem & 63;
            const int bb  = gm0 >> 11;
            const int t0  = gm0 & 2047;
            if (sel == 2) {
                bf16x4 p;
                #pragma unroll
                for (int r = 0; r < 4; r++) p[r] = (bf16)(acc[i][j][r] + bias[gn]);
                *(bf16x4*)&VbT[((size_t)(bb * NH + h) * HD + hd) * SEQ + t0] = p;
            } else {
                #pragma unroll
                for (int r = 0; r < 4; r++) {
                    float v = acc[i][j][r] + bias[gn];
                    size_t idx = ((size_t)(bb * NH + h) * SEQ + t0 + r) * HD + hd;
                    if (sel == 0) Qb[idx] = (bf16)(v * QSCALE);
                    else          Kb[idx] = (bf16)v;
                }
            }
        }
    }
}

// ---------------------------------------------------------------------------
// Kernel 2: causal flash attention — R4 chassis (LDS-staged shared K/V,
// 4 waves x 16 q, 2 barriers/tile, 16 waves/CU) + no-max softmax with HW
// exp (v_exp_f32): zero shfls / alpha / rescale in the loop. Transposed
// scores S^T = K·Q^T (in-lane softmax). Plain launch_bounds(256): the
// min-waves attr pinned VGPR=64 and spilled everything in R8/R9.
// ---------------------------------------------------------------------------
__global__ __launch_bounds__(256)
void k_attn(const bf16* __restrict__ Qb, const bf16* __restrict__ Kb,
            const bf16* __restrict__ VbT, bf16* __restrict__ AO)
{
    __shared__ bf16 Ks[64][72];    // [key][hd], padded
    __shared__ bf16 Vt[64][72];    // [hd][key], padded
    __shared__ bf16 Ps[64][72];    // [q][key], wave-local 16-row strips

    const int tid  = threadIdx.x;
    const int wv   = tid >> 6;
    const int lane = tid & 63;
    const int lr   = lane & 15;
    const int lk   = lane >> 4;
    const int bh   = blockIdx.y;
    const int qt   = ((bh >> 3) & 1) ? (31 - (int)blockIdx.x) : (int)blockIdx.x;

    const bf16* Qp  = Qb  + (size_t)bh * SEQ * HD;
    const bf16* Kp  = Kb  + (size_t)bh * SEQ * HD;
    const bf16* Vtp = VbT + (size_t)bh * HD * SEQ;

    const int qg = qt * 64 + wv * 16 + lr;    // this lane's query row

    // Q as B-operand: b[n=lr][k=lk*8+e] (loop-invariant)
    bf16x8 qf[2];
    qf[0] = *(const bf16x8*)&Qp[(size_t)qg * HD +      lk * 8];
    qf[1] = *(const bf16x8*)&Qp[(size_t)qg * HD + 32 + lk * 8];

    f32x4 ot[4] = {};          // O^T: col=q(=lr), row=hd=jh*16+lk*4+r
    float lsum = 0.f;

    const int r0 = tid >> 3;          // 0..31
    const int c0 = (tid & 7) * 8;

    for (int kt = 0; kt <= qt; kt++) {
        const int k0 = kt * 64;
        __syncthreads();
        *(bf16x8*)&Ks[r0     ][c0] = *(const bf16x8*)&Kp[(size_t)(k0 + r0     ) * HD + c0];
        *(bf16x8*)&Ks[r0 + 32][c0] = *(const bf16x8*)&Kp[(size_t)(k0 + r0 + 32) * HD + c0];
        *(bf16x8*)&Vt[r0     ][c0] = *(const bf16x8*)&Vtp[(size_t)(r0     ) * SEQ + k0 + c0];
        *(bf16x8*)&Vt[r0 + 32][c0] = *(const bf16x8*)&Vtp[(size_t)(r0 + 32) * SEQ + k0 + c0];
        __syncthreads();

        // S^T[key][q]: A = K rows (LDS), B = Q frags; row=key=j*16+lk*4+r, col=q=lr
        f32x4 s[4] = {};
        #pragma unroll
        for (int j = 0; j < 4; j++) {
            #pragma unroll
            for (int c = 0; c < 2; c++) {
                bf16x8 ka = *(const bf16x8*)&Ks[j * 16 + lr][c * 32 + lk * 8];
                s[j] = MFMA16(ka, qf[c], s[j]);
            }
        }

        // no-max softmax with HW exp; masked -> 0 on the diagonal tile
        const bool diag = (kt == qt);
        #pragma unroll
        for (int j = 0; j < 4; j++) {
            const int keyb = k0 + j * 16 + lk * 4;
            f32x4 p;
            #pragma unroll
            for (int r = 0; r < 4; r++) {
                float e = __builtin_amdgcn_exp2f(s[j][r]);
                if (diag) e = (keyb + r > qg) ? 0.f : e;
                p[r] = e;
            }
            s[j] = p;
            lsum += (p[0] + p[1]) + (p[2] + p[3]);
        }

        // P -> LDS [q][key], packed b64 (wave-local rows; no barrier needed)
        #pragma unroll
        for (int j = 0; j < 4; j++) {
            bf16x4 p4 = { (bf16)s[j][0], (bf16)s[j][1], (bf16)s[j][2], (bf16)s[j][3] };
            *(bf16x4*)&Ps[wv * 16 + lr][j * 16 + lk * 4] = p4;
        }

        // O^T += Vt · P^T : MFMA(a = Vt rows [hd][key], b = Ps rows [q][key])
        #pragma unroll
        for (int c = 0; c < 2; c++) {
            bf16x8 pb = *(const bf16x8*)&Ps[wv * 16 + lr][c * 32 + lk * 8];
            #pragma unroll
            for (int jh = 0; jh < 4; jh++) {
                bf16x8 va = *(const bf16x8*)&Vt[jh * 16 + lr][c * 32 + lk * 8];
                ot[jh] = MFMA16(va, pb, ot[jh]);
            }
        }
    }

    // final l reduction: 2 shfls once per kernel (lanes lr, lr+16, lr+32, lr+48)
    lsum += __shfl_xor(lsum, 16);
    lsum += __shfl_xor(lsum, 32);

    // epilogue: AO[b, q, h_*64 + hd] = O/l ; lane writes 4 consecutive hd (b64)
    const float inv = 1.0f / lsum;
    const int b_ = bh >> 4, h_ = bh & 15;
    const size_t base = ((size_t)(b_ * SEQ + qg)) * D_MODEL + h_ * HD;
    #pragma unroll
    for (int jh = 0; jh < 4; jh++) {
        bf16x4 o4 = { (bf16)(ot[jh][0] * inv), (bf16)(ot[jh][1] * inv),
                      (bf16)(ot[jh][2] * inv), (bf16)(ot[jh][3] * inv) };
        *(bf16x4*)&AO[base + jh * 16 + lk * 4] = o4;
    }
}

// ---------------------------------------------------------------------------
// Kernel 3: output projection, 128x64 tile, BK=32, global_load_lds staging.
// ---------------------------------------------------------------------------
__global__ __launch_bounds__(256)
void k_oproj(const bf16* __restrict__ a_, const bf16* __restrict__ w,
             const float* __restrict__ bias, float* __restrict__ out)
{
    __shared__ bf16 As[128 * 32];
    __shared__ bf16 Ws[64 * 32];

    const int tid  = threadIdx.x;
    const int wv   = tid >> 6;
    const int lane = tid & 63;
    const int lr   = lane & 15;
    const int lk   = lane >> 4;
    const int wm   = wv >> 1, wn = wv & 1;
    const int m0   = blockIdx.x * 128;
    const int n0   = blockIdx.y * 64;

    const int sRow = tid >> 2;
    const int sCol = (tid & 3) * 8;
    const int sOff = sRow * 32 + sCol;

    f32x4 acc[4][2] = {};

    for (int kt = 0; kt < 1024; kt += 32) {
        __syncthreads();
        async16(&a_[(size_t)(m0 + sRow     ) * 1024 + kt + sCol], &As[sOff]);
        async16(&a_[(size_t)(m0 + 64 + sRow) * 1024 + kt + sCol], &As[64 * 32 + sOff]);
        async16(&w [(size_t)(n0 + sRow     ) * 1024 + kt + sCol], &Ws[sOff]);
        __syncthreads();

        bf16x8 a[4], b[2];
        #pragma unroll
        for (int i = 0; i < 4; i++)
            a[i] = *(const bf16x8*)&As[(wm * 64 + i * 16 + lr) * 32 + lk * 8];
        #pragma unroll
        for (int j = 0; j < 2; j++)
            b[j] = *(const bf16x8*)&Ws[(wn * 32 + j * 16 + lr) * 32 + lk * 8];
        #pragma unroll
        for (int i = 0; i < 4; i++)
            #pragma unroll
            for (int j = 0; j < 2; j++)
                acc[i][j] = MFMA16(a[i], b[j], acc[i][j]);
    }

    #pragma unroll
    for (int i = 0; i < 4; i++) {
        #pragma unroll
        for (int j = 0; j < 2; j++) {
            #pragma unroll
            for (int r = 0; r < 4; r++) {
                int gm = m0 + wm * 64 + i * 16 + lk * 4 + r;
                int gn = n0 + wn * 32 + j * 16 + lr;
                out[(size_t)gm * 1024 + gn] = acc[i][j][r] + bias[gn];
            }
        }
    }
}

// ---------------------------------------------------------------------------
extern "C" void kernel_launch(void* const* d_in, const int* in_sizes, int n_in,
                              void* d_out, int out_size, void* d_ws, size_t ws_size,
                              hipStream_t stream)
{
    const float* x     = (const float*)d_in[0];
    const float* qkv_w = (const float*)d_in[1];
    const float* qkv_b = (const float*)d_in[2];
    const float* out_w = (const float*)d_in[3];
    const float* out_b = (const float*)d_in[4];
    float* out = (float*)d_out;

    const size_t SZ = (size_t)NB * NH * SEQ * HD;      // 4,194,304
    bf16* Qb  = (bf16*)d_ws;
    bf16* Kb  = Qb + SZ;
    bf16* VbT = Kb + SZ;
    bf16* AO  = VbT + SZ;
    bf16* xb  = AO + SZ;
    bf16* wqb = xb + SZ;
    bf16* wob = wqb + (size_t)3 * D_MODEL * D_MODEL;

    hipLaunchKernelGGL(k_cast, dim3(2048), dim3(256), 0, stream, x,     xb,  524288);
    hipLaunchKernelGGL(k_cast, dim3(1536), dim3(256), 0, stream, qkv_w, wqb, 393216);
    hipLaunchKernelGGL(k_cast, dim3(512),  dim3(256), 0, stream, out_w, wob, 131072);

    hipLaunchKernelGGL(k_qkv, dim3(32, 24), dim3(256), 0, stream,
                       xb, wqb, qkv_b, Qb, Kb, VbT);
    hipLaunchKernelGGL(k_attn, dim3(32, 32), dim3(256), 0, stream,
                       Qb, Kb, VbT, AO);
    hipLaunchKernelGGL(k_oproj, dim3(32, 16), dim3(256), 0, stream,
                       AO, wob, out_b, out);
}